// Round 3
// baseline (276.376 us; speedup 1.0000x reference)
//
#include <hip/hip_runtime.h>
#include <math.h>

#define LEN_Q 13294
#define NFRAMES 2
#define MTOT (LEN_Q * NFRAMES)   // 26588
#define DMODEL 256
#define HEADS 8
#define LEVELS 4
#define POINTS 4

typedef __attribute__((ext_vector_type(8))) short short8;
typedef __attribute__((ext_vector_type(4))) float f32x4;
typedef __attribute__((ext_vector_type(2))) unsigned int uint2v;
typedef __attribute__((ext_vector_type(4))) unsigned short ushort4v;

__device__ __forceinline__ unsigned short f2bf(float x) {
    unsigned u = __builtin_bit_cast(unsigned, x);
    unsigned r = (u + 0x7fffu + ((u >> 16) & 1u)) >> 16;
    return (unsigned short)r;
}
__device__ __forceinline__ float bf2f(unsigned short b) {
    return __builtin_bit_cast(float, (unsigned)b << 16);
}

// ---------------------------------------------------------------------------
// f32 -> bf16 elementwise convert
// ---------------------------------------------------------------------------
__global__ __launch_bounds__(256) void cvt_bf16(const float* __restrict__ in,
                                                unsigned short* __restrict__ out, int n)
{
    int i = (blockIdx.x * 256 + threadIdx.x) * 4;
    if (i + 3 < n) {
        f32x4 v = *(const f32x4*)(in + i);
        ushort4v o;
        o.x = f2bf(v.x); o.y = f2bf(v.y); o.z = f2bf(v.z); o.w = f2bf(v.w);
        *(ushort4v*)(out + i) = o;
    } else {
        for (int j = i; j < n; ++j) out[j] = f2bf(in[j]);
    }
}

// ---------------------------------------------------------------------------
// B[K,N] f32 -> BT[N,K] bf16   (K == 256; one block per n)
// ---------------------------------------------------------------------------
__global__ __launch_bounds__(256) void transpose_cvt(const float* __restrict__ B,
                                                     unsigned short* __restrict__ BT,
                                                     int K, int N)
{
    int n = blockIdx.x;
    int k = threadIdx.x;
    if (k < K) BT[(size_t)n * K + k] = f2bf(B[(size_t)k * N + n]);
}

// ---------------------------------------------------------------------------
// bf16 MFMA GEMM v2: C[M,N] = A[M,K] @ BT[N,K]^T + bias
// 256-thread blocks = 4 waves; block tile 128(M) x 64(N); wave tile 32x64
// (2x4 grid of 16x16x32 MFMAs). No LDS; B rows L1/L2-resident.
// Dual bias: col n gets bias1[n] if n<nsplit else bias2[n-nsplit].
// ---------------------------------------------------------------------------
template <bool OUT_BF16>
__global__ __launch_bounds__(256, 2) void gemm2(
    const unsigned short* __restrict__ A,
    const unsigned short* __restrict__ BT,
    const float* __restrict__ bias1,
    const float* __restrict__ bias2, int nsplit,
    void* __restrict__ C, int M, int N, int K)
{
    const int w = threadIdx.x >> 6;
    const int L = threadIdx.x & 63;
    const int m_base = blockIdx.y * 128 + w * 32;
    const int n_base = blockIdx.x * 64;
    const int lrow = L & 15;
    const int kq = (L >> 4) * 8;

    f32x4 acc[2][4];
    #pragma unroll
    for (int i = 0; i < 2; ++i)
        #pragma unroll
        for (int j = 0; j < 4; ++j) acc[i][j] = (f32x4){0.f, 0.f, 0.f, 0.f};

    const unsigned short* arow[2];
    #pragma unroll
    for (int i = 0; i < 2; ++i) {
        int r = m_base + i * 16 + lrow;
        if (r > M - 1) r = M - 1;          // clamp; stores guarded
        arow[i] = A + (size_t)r * K + kq;
    }
    const unsigned short* brow[4];
    #pragma unroll
    for (int j = 0; j < 4; ++j) {
        int r = n_base + j * 16 + lrow;    // N multiple of 64 -> valid
        brow[j] = BT + (size_t)r * K + kq;
    }

    for (int k0 = 0; k0 < K; k0 += 32) {
        short8 af[2], bf[4];
        #pragma unroll
        for (int i = 0; i < 2; ++i) af[i] = *(const short8*)(arow[i] + k0);
        #pragma unroll
        for (int j = 0; j < 4; ++j) bf[j] = *(const short8*)(brow[j] + k0);
        #pragma unroll
        for (int i = 0; i < 2; ++i)
            #pragma unroll
            for (int j = 0; j < 4; ++j)
                acc[i][j] = __builtin_amdgcn_mfma_f32_16x16x32_bf16(af[i], bf[j], acc[i][j], 0, 0, 0);
    }

    const int mrow0 = (L >> 4) * 4;
    #pragma unroll
    for (int i = 0; i < 2; ++i) {
        #pragma unroll
        for (int r = 0; r < 4; ++r) {
            int m = m_base + i * 16 + mrow0 + r;
            if (m < M) {
                #pragma unroll
                for (int j = 0; j < 4; ++j) {
                    int n = n_base + j * 16 + lrow;
                    float b = (n < nsplit) ? bias1[n] : bias2[n - nsplit];
                    float v = acc[i][j][r] + b;
                    if (OUT_BF16) ((unsigned short*)C)[(size_t)m * N + n] = f2bf(v);
                    else          ((float*)C)[(size_t)m * N + n] = v;
                }
            }
        }
    }
}

// ---------------------------------------------------------------------------
// Sampler v3: block = 4 waves, one row per wave. (weight,idx) packed as int2
// in LDS laid out [slot=lp*4+cr][h]: gather reads are ds_read_b64 with the 8
// heads on 8 distinct banks (8-lane broadcast within a head) -> conflict-free.
// off/attn read from fused [row][384] buffer (cols 0-255 off, 256-383 attn).
// ---------------------------------------------------------------------------
__global__ __launch_bounds__(256) void sample3(
    const unsigned short* __restrict__ value,  // bf16 [MTOT,256]
    const unsigned short* __restrict__ oa,     // bf16 [MTOT,384]
    const float* __restrict__ refpts,          // [LEN_Q, LEVELS, 2]
    const int*   __restrict__ spatial,         // [LEVELS,2] (H,W)
    const int*   __restrict__ lsi,             // [LEVELS]
    unsigned short* __restrict__ samp)         // bf16 [MTOT,256]
{
    const int w = threadIdx.x >> 6;
    const int L = threadIdx.x & 63;
    const int row = blockIdx.x * 4 + w;        // MTOT = 4*6647 exactly
    const int frame = row >= LEN_Q ? 1 : 0;
    const int q = row - frame * LEN_Q;

    __shared__ float attn_s[4][HEADS][16];
    __shared__ float loc_s[4][HEADS][16][2];
    __shared__ int2  wi_s[4][64][8];           // [slot = lp*4+cr][h]

    // ---- phase 1: off -> loc, attn -> LDS ----
    {
        uint2v ov = *(const uint2v*)(oa + (size_t)row * 384 + 4 * L);
        float o[4];
        o[0] = bf2f((unsigned short)(ov.x & 0xffffu));
        o[1] = bf2f((unsigned short)(ov.x >> 16));
        o[2] = bf2f((unsigned short)(ov.y & 0xffffu));
        o[3] = bf2f((unsigned short)(ov.y >> 16));
        #pragma unroll
        for (int i = 0; i < 4; ++i) {
            int t = 4 * L + i;
            int c = t & 1;
            int l = (t >> 3) & 3;
            int h = t >> 5;
            int lp = (t >> 1) & 15;
            float r = refpts[((size_t)q * LEVELS + l) * 2 + c];
            int dim = spatial[l * 2 + (c ^ 1)];   // c==0 -> W, c==1 -> H
            loc_s[w][h][lp][c] = r + o[i] / (float)dim;
        }
        unsigned av = *(const unsigned*)(oa + (size_t)row * 384 + 256 + 2 * L);
        int t0 = 2 * L;
        attn_s[w][t0 >> 4][t0 & 15] = bf2f((unsigned short)(av & 0xffffu));
        attn_s[w][(t0 + 1) >> 4][(t0 + 1) & 15] = bf2f((unsigned short)(av >> 16));
    }
    __syncthreads();

    // ---- phase 2: softmax per head ----
    if (L < 8) {
        float m = attn_s[w][L][0];
        #pragma unroll
        for (int i = 1; i < 16; ++i) m = fmaxf(m, attn_s[w][L][i]);
        float e[16]; float s = 0.f;
        #pragma unroll
        for (int i = 0; i < 16; ++i) { e[i] = __expf(attn_s[w][L][i] - m); s += e[i]; }
        float inv = 1.f / s;
        #pragma unroll
        for (int i = 0; i < 16; ++i) attn_s[w][L][i] = e[i] * inv;
    }
    __syncthreads();

    // ---- phase 3: corner idx + weight (2 (h,lp) entries per lane) ----
    #pragma unroll
    for (int i = 0; i < 2; ++i) {
        int e = 2 * L + i;
        int h = e >> 4;
        int lp = e & 15;
        int l = lp >> 2;
        int Hl = spatial[l * 2], Wl = spatial[l * 2 + 1];
        int start = lsi[l];
        float wt = attn_s[w][h][lp];
        float x = loc_s[w][h][lp][0] * (float)Wl - 0.5f;
        float y = loc_s[w][h][lp][1] * (float)Hl - 0.5f;
        float x0f = floorf(x), y0f = floorf(y);
        float lx = x - x0f, ly = y - y0f;
        int x0 = (int)x0f, y0 = (int)y0f;
        int x1 = x0 + 1, y1 = y0 + 1;
        int vx0 = (x0 >= 0) & (x0 < Wl);
        int vx1 = (x1 >= 0) & (x1 < Wl);
        int vy0 = (y0 >= 0) & (y0 < Hl);
        int vy1 = (y1 >= 0) & (y1 < Hl);
        int x0c = min(max(x0, 0), Wl - 1);
        int x1c = min(max(x1, 0), Wl - 1);
        int y0c = min(max(y0, 0), Hl - 1);
        int y1c = min(max(y1, 0), Hl - 1);
        float w00 = (vy0 & vx0) ? wt * (1.f - lx) * (1.f - ly) : 0.f;
        float w01 = (vy0 & vx1) ? wt * lx * (1.f - ly) : 0.f;
        float w10 = (vy1 & vx0) ? wt * (1.f - lx) * ly : 0.f;
        float w11 = (vy1 & vx1) ? wt * lx * ly : 0.f;
        int slot = lp * 4;
        wi_s[w][slot + 0][h] = make_int2(__float_as_int(w00), start + y0c * Wl + x0c);
        wi_s[w][slot + 1][h] = make_int2(__float_as_int(w01), start + y0c * Wl + x1c);
        wi_s[w][slot + 2][h] = make_int2(__float_as_int(w10), start + y1c * Wl + x0c);
        wi_s[w][slot + 3][h] = make_int2(__float_as_int(w11), start + y1c * Wl + x1c);
    }
    __syncthreads();

    // ---- phase 4: gather (bf16x4 per lane, conflict-free b64 LDS reads) ----
    const int h = L >> 3;
    const unsigned short* vbase = value + (size_t)frame * LEN_Q * 256 + 4 * L;
    float a0 = 0.f, a1 = 0.f, a2 = 0.f, a3 = 0.f;
    #pragma unroll 8
    for (int s = 0; s < 64; ++s) {
        int2 wi = wi_s[w][s][h];
        float wt = __int_as_float(wi.x);
        uint2v v = *(const uint2v*)(vbase + (size_t)wi.y * 256);
        a0 = fmaf(wt, __builtin_bit_cast(float, v.x << 16), a0);
        a1 = fmaf(wt, __builtin_bit_cast(float, v.x & 0xffff0000u), a1);
        a2 = fmaf(wt, __builtin_bit_cast(float, v.y << 16), a2);
        a3 = fmaf(wt, __builtin_bit_cast(float, v.y & 0xffff0000u), a3);
    }
    ushort4v o;
    o.x = f2bf(a0); o.y = f2bf(a1); o.z = f2bf(a2); o.w = f2bf(a3);
    *(ushort4v*)(samp + (size_t)row * 256 + 4 * L) = o;
}

// ---------------------------------------------------------------------------
extern "C" void kernel_launch(void* const* d_in, const int* in_sizes, int n_in,
                              void* d_out, int out_size, void* d_ws, size_t ws_size,
                              hipStream_t stream)
{
    const float* query   = (const float*)d_in[0];
    const float* refpts  = (const float*)d_in[1];
    const float* inflat  = (const float*)d_in[2];
    const int*   spatial = (const int*)d_in[3];
    const int*   lsi     = (const int*)d_in[4];
    const float* Wv      = (const float*)d_in[5];
    const float* bv      = (const float*)d_in[6];
    const float* Woff    = (const float*)d_in[7];
    const float* boff    = (const float*)d_in[8];
    const float* Wattn   = (const float*)d_in[9];
    const float* battn   = (const float*)d_in[10];
    const float* Wout    = (const float*)d_in[11];
    const float* bout    = (const float*)d_in[12];

    unsigned short* ws = (unsigned short*)d_ws;
    const size_t MR = (size_t)MTOT * 256;
    unsigned short* q16    = ws;                       // MTOT*256
    unsigned short* in16   = q16 + MR;                 // MTOT*256
    unsigned short* v16    = in16 + MR;                // MTOT*256
    unsigned short* oa16   = v16 + MR;                 // MTOT*384 (off|attn)
    unsigned short* samp16 = oa16 + (size_t)MTOT * 384;// MTOT*256
    unsigned short* wvT    = samp16 + MR;              // 256*256
    unsigned short* woaT   = wvT + 65536;              // 384*256
    unsigned short* woutT  = woaT + 98304;             // 256*256

    const int nElem = MTOT * 256;                      // divisible by 1024
    dim3 blk256(256);

    hipLaunchKernelGGL(cvt_bf16, dim3(nElem / 1024), blk256, 0, stream, query,  q16,  nElem);
    hipLaunchKernelGGL(cvt_bf16, dim3(nElem / 1024), blk256, 0, stream, inflat, in16, nElem);
    hipLaunchKernelGGL(transpose_cvt, dim3(256), blk256, 0, stream, Wv,    wvT,          256, 256);
    hipLaunchKernelGGL(transpose_cvt, dim3(256), blk256, 0, stream, Woff,  woaT,         256, 256);
    hipLaunchKernelGGL(transpose_cvt, dim3(128), blk256, 0, stream, Wattn, woaT + 65536, 256, 128);
    hipLaunchKernelGGL(transpose_cvt, dim3(256), blk256, 0, stream, Wout,  woutT,        256, 256);

    const int mBlocks = (MTOT + 127) / 128;            // 208
    hipLaunchKernelGGL((gemm2<true>),  dim3(4, mBlocks), blk256, 0, stream,
                       in16, wvT, bv, bv, 256, (void*)v16, MTOT, 256, 256);
    hipLaunchKernelGGL((gemm2<true>),  dim3(6, mBlocks), blk256, 0, stream,
                       q16, woaT, boff, battn, 256, (void*)oa16, MTOT, 384, 256);

    hipLaunchKernelGGL(sample3, dim3(MTOT / 4), blk256, 0, stream,
                       v16, oa16, refpts, spatial, lsi, samp16);

    hipLaunchKernelGGL((gemm2<false>), dim3(4, mBlocks), blk256, 0, stream,
                       samp16, woutT, bout, bout, 256, d_out, MTOT, 256, 256);
}

// Round 4
// 256.835 us; speedup vs baseline: 1.0761x; 1.0761x over previous
//
#include <hip/hip_runtime.h>
#include <math.h>

#define LEN_Q 13294
#define NFRAMES 2
#define MTOT (LEN_Q * NFRAMES)   // 26588
#define DMODEL 256
#define HEADS 8
#define LEVELS 4
#define POINTS 4

typedef __attribute__((ext_vector_type(8))) short short8;
typedef __attribute__((ext_vector_type(4))) float f32x4;
typedef __attribute__((ext_vector_type(2))) unsigned int uint2v;
typedef __attribute__((ext_vector_type(4))) unsigned short ushort4v;

__device__ __forceinline__ unsigned short f2bf(float x) {
    unsigned u = __builtin_bit_cast(unsigned, x);
    unsigned r = (u + 0x7fffu + ((u >> 16) & 1u)) >> 16;
    return (unsigned short)r;
}
__device__ __forceinline__ float bf2f(unsigned short b) {
    return __builtin_bit_cast(float, (unsigned)b << 16);
}

// ---------------------------------------------------------------------------
// f32 -> bf16 elementwise convert
// ---------------------------------------------------------------------------
__global__ __launch_bounds__(256) void cvt_bf16(const float* __restrict__ in,
                                                unsigned short* __restrict__ out, int n)
{
    int i = (blockIdx.x * 256 + threadIdx.x) * 4;
    if (i + 3 < n) {
        f32x4 v = *(const f32x4*)(in + i);
        ushort4v o;
        o.x = f2bf(v.x); o.y = f2bf(v.y); o.z = f2bf(v.z); o.w = f2bf(v.w);
        *(ushort4v*)(out + i) = o;
    } else {
        for (int j = i; j < n; ++j) out[j] = f2bf(in[j]);
    }
}

// ---------------------------------------------------------------------------
// B[K,N] f32 -> BT[N,K] bf16   (K == 256; one block per n)
// ---------------------------------------------------------------------------
__global__ __launch_bounds__(256) void transpose_cvt(const float* __restrict__ B,
                                                     unsigned short* __restrict__ BT,
                                                     int K, int N)
{
    int n = blockIdx.x;
    int k = threadIdx.x;
    if (k < K) BT[(size_t)n * K + k] = f2bf(B[(size_t)k * N + n]);
}

// ---------------------------------------------------------------------------
// gemm3: LDS-staged MFMA GEMM (m93-ladder structure).
// C[M,N] = A[M,K] @ BT[N,K]^T + bias.  256 threads = 4 waves.
// Block tile 128x128, BK=32; wave computes a 64x64 quadrant via 4x4 grid of
// 16x16x32 bf16 MFMAs. LDS: As[128][32] + Bs[128][32] bf16 = 16 KB.
// Column-split outputs: cols [0,n1) -> C1 (row stride n1), cols [n1,N) -> C2
// (row stride N-n1); bias likewise split. Pass n1==N for a single output.
// ---------------------------------------------------------------------------
template <bool OUT_BF16>
__global__ __launch_bounds__(256, 2) void gemm3(
    const unsigned short* __restrict__ A,
    const unsigned short* __restrict__ BT,
    const float* __restrict__ bias1,
    const float* __restrict__ bias2, int n1,
    void* __restrict__ C1, void* __restrict__ C2,
    int M, int N, int K)
{
    __shared__ unsigned short As[128 * 32];
    __shared__ unsigned short Bs[128 * 32];

    const int t = threadIdx.x;
    const int w = t >> 6;
    const int L = t & 63;
    const int m0 = blockIdx.y * 128;
    const int n0 = blockIdx.x * 128;

    // staging: thread t -> row (t>>1), element chunk (t&1)*16 .. +16 (two 16B loads)
    const int sr = t >> 1;
    const int sc = (t & 1) * 16;
    int arow = m0 + sr; if (arow > M - 1) arow = M - 1;   // clamp; stores guarded
    const unsigned short* Ag = A + (size_t)arow * K + sc;
    const unsigned short* Bg = BT + (size_t)(n0 + sr) * K + sc;  // N % 128 == 0
    unsigned short* AsW = &As[sr * 32 + sc];
    unsigned short* BsW = &Bs[sr * 32 + sc];

    // wave quadrant within the 128x128 tile
    const int mq = (w & 1) * 64;
    const int nq = (w >> 1) * 64;
    const int lr = L & 15;
    const int kq = (L >> 4) * 8;

    f32x4 acc[4][4];
    #pragma unroll
    for (int i = 0; i < 4; ++i)
        #pragma unroll
        for (int j = 0; j < 4; ++j) acc[i][j] = (f32x4){0.f, 0.f, 0.f, 0.f};

    for (int k0 = 0; k0 < K; k0 += 32) {
        short8 av0 = *(const short8*)(Ag + k0);
        short8 av1 = *(const short8*)(Ag + k0 + 8);
        short8 bv0 = *(const short8*)(Bg + k0);
        short8 bv1 = *(const short8*)(Bg + k0 + 8);
        __syncthreads();                 // previous iteration's reads done
        *(short8*)(AsW) = av0;
        *(short8*)(AsW + 8) = av1;
        *(short8*)(BsW) = bv0;
        *(short8*)(BsW + 8) = bv1;
        __syncthreads();                 // tile visible

        short8 af[4], bf[4];
        #pragma unroll
        for (int i = 0; i < 4; ++i)
            af[i] = *(const short8*)&As[(mq + i * 16 + lr) * 32 + kq];
        #pragma unroll
        for (int j = 0; j < 4; ++j)
            bf[j] = *(const short8*)&Bs[(nq + j * 16 + lr) * 32 + kq];
        #pragma unroll
        for (int i = 0; i < 4; ++i)
            #pragma unroll
            for (int j = 0; j < 4; ++j)
                acc[i][j] = __builtin_amdgcn_mfma_f32_16x16x32_bf16(af[i], bf[j], acc[i][j], 0, 0, 0);
    }

    // epilogue: C/D layout col = L&15, row = (L>>4)*4 + r
    const int rr = (L >> 4) * 4;
    const int n2w = N - n1;
    #pragma unroll
    for (int i = 0; i < 4; ++i) {
        #pragma unroll
        for (int r = 0; r < 4; ++r) {
            int m = m0 + mq + i * 16 + rr + r;
            if (m < M) {
                #pragma unroll
                for (int j = 0; j < 4; ++j) {
                    int n = n0 + nq + j * 16 + lr;
                    float b = (n < n1) ? bias1[n] : bias2[n - n1];
                    float v = acc[i][j][r] + b;
                    if (n < n1) {
                        if (OUT_BF16) ((unsigned short*)C1)[(size_t)m * n1 + n] = f2bf(v);
                        else          ((float*)C1)[(size_t)m * n1 + n] = v;
                    } else {
                        if (OUT_BF16) ((unsigned short*)C2)[(size_t)m * n2w + (n - n1)] = f2bf(v);
                        else          ((float*)C2)[(size_t)m * n2w + (n - n1)] = v;
                    }
                }
            }
        }
    }
}

// ---------------------------------------------------------------------------
// Sampler (R2 version, measured 69.6 us): block = 4 waves, one row per wave.
// Lane L: head h = L>>3, 4 channels (4L..4L+3), bf16x4 (8B) gathers.
// ---------------------------------------------------------------------------
__global__ __launch_bounds__(256) void sample2(
    const unsigned short* __restrict__ value,  // bf16 [MTOT,256]
    const unsigned short* __restrict__ off,    // bf16 [MTOT,256]
    const unsigned short* __restrict__ attn,   // bf16 [MTOT,128]
    const float* __restrict__ refpts,          // [LEN_Q, LEVELS, 2]
    const int*   __restrict__ spatial,         // [LEVELS,2] (H,W)
    const int*   __restrict__ lsi,             // [LEVELS]
    unsigned short* __restrict__ samp)         // bf16 [MTOT,256]
{
    const int w = threadIdx.x >> 6;
    const int L = threadIdx.x & 63;
    const int row = blockIdx.x * 4 + w;        // MTOT = 4*6647 exactly
    const int frame = row >= LEN_Q ? 1 : 0;
    const int q = row - frame * LEN_Q;

    __shared__ float attn_s[4][HEADS][16];
    __shared__ float loc_s[4][HEADS][16][2];
    __shared__ float w_s[4][HEADS][16][4];
    __shared__ int   idx_s[4][HEADS][16][4];

    // ---- phase 1: off -> loc, attn -> LDS ----
    {
        uint2v ov = *(const uint2v*)(off + (size_t)row * 256 + 4 * L);
        float o[4];
        o[0] = bf2f((unsigned short)(ov.x & 0xffffu));
        o[1] = bf2f((unsigned short)(ov.x >> 16));
        o[2] = bf2f((unsigned short)(ov.y & 0xffffu));
        o[3] = bf2f((unsigned short)(ov.y >> 16));
        #pragma unroll
        for (int i = 0; i < 4; ++i) {
            int tt = 4 * L + i;
            int c = tt & 1;
            int l = (tt >> 3) & 3;
            int h = tt >> 5;
            int lp = (tt >> 1) & 15;
            float r = refpts[((size_t)q * LEVELS + l) * 2 + c];
            int dim = spatial[l * 2 + (c ^ 1)];   // c==0 -> W, c==1 -> H
            loc_s[w][h][lp][c] = r + o[i] / (float)dim;
        }
        unsigned av = *(const unsigned*)(attn + (size_t)row * 128 + 2 * L);
        int t0 = 2 * L;
        attn_s[w][t0 >> 4][t0 & 15] = bf2f((unsigned short)(av & 0xffffu));
        attn_s[w][(t0 + 1) >> 4][(t0 + 1) & 15] = bf2f((unsigned short)(av >> 16));
    }
    __syncthreads();

    // ---- phase 2: softmax per head ----
    if (L < 8) {
        float m = attn_s[w][L][0];
        #pragma unroll
        for (int i = 1; i < 16; ++i) m = fmaxf(m, attn_s[w][L][i]);
        float e[16]; float s = 0.f;
        #pragma unroll
        for (int i = 0; i < 16; ++i) { e[i] = __expf(attn_s[w][L][i] - m); s += e[i]; }
        float inv = 1.f / s;
        #pragma unroll
        for (int i = 0; i < 16; ++i) attn_s[w][L][i] = e[i] * inv;
    }
    __syncthreads();

    // ---- phase 3: corner idx + weight (2 entries per lane) ----
    #pragma unroll
    for (int i = 0; i < 2; ++i) {
        int e = 2 * L + i;
        int h = e >> 4;
        int lp = e & 15;
        int l = lp >> 2;
        int Hl = spatial[l * 2], Wl = spatial[l * 2 + 1];
        int start = lsi[l];
        float wt = attn_s[w][h][lp];
        float x = loc_s[w][h][lp][0] * (float)Wl - 0.5f;
        float y = loc_s[w][h][lp][1] * (float)Hl - 0.5f;
        float x0f = floorf(x), y0f = floorf(y);
        float lx = x - x0f, ly = y - y0f;
        int x0 = (int)x0f, y0 = (int)y0f;
        int x1 = x0 + 1, y1 = y0 + 1;
        int vx0 = (x0 >= 0) & (x0 < Wl);
        int vx1 = (x1 >= 0) & (x1 < Wl);
        int vy0 = (y0 >= 0) & (y0 < Hl);
        int vy1 = (y1 >= 0) & (y1 < Hl);
        int x0c = min(max(x0, 0), Wl - 1);
        int x1c = min(max(x1, 0), Wl - 1);
        int y0c = min(max(y0, 0), Hl - 1);
        int y1c = min(max(y1, 0), Hl - 1);
        idx_s[w][h][lp][0] = start + y0c * Wl + x0c;
        idx_s[w][h][lp][1] = start + y0c * Wl + x1c;
        idx_s[w][h][lp][2] = start + y1c * Wl + x0c;
        idx_s[w][h][lp][3] = start + y1c * Wl + x1c;
        w_s[w][h][lp][0] = (vy0 & vx0) ? wt * (1.f - lx) * (1.f - ly) : 0.f;
        w_s[w][h][lp][1] = (vy0 & vx1) ? wt * lx * (1.f - ly) : 0.f;
        w_s[w][h][lp][2] = (vy1 & vx0) ? wt * (1.f - lx) * ly : 0.f;
        w_s[w][h][lp][3] = (vy1 & vx1) ? wt * lx * ly : 0.f;
    }
    __syncthreads();

    // ---- phase 4: gather (bf16x4 per lane) ----
    const int h = L >> 3;
    const unsigned short* vbase = value + (size_t)frame * LEN_Q * 256 + 4 * L;
    float a0 = 0.f, a1 = 0.f, a2 = 0.f, a3 = 0.f;
    #pragma unroll
    for (int lp = 0; lp < 16; ++lp) {
        #pragma unroll
        for (int cr = 0; cr < 4; ++cr) {
            float wt = w_s[w][h][lp][cr];
            int idx = idx_s[w][h][lp][cr];
            uint2v v = *(const uint2v*)(vbase + (size_t)idx * 256);
            a0 = fmaf(wt, __builtin_bit_cast(float, v.x << 16), a0);
            a1 = fmaf(wt, __builtin_bit_cast(float, v.x & 0xffff0000u), a1);
            a2 = fmaf(wt, __builtin_bit_cast(float, v.y << 16), a2);
            a3 = fmaf(wt, __builtin_bit_cast(float, v.y & 0xffff0000u), a3);
        }
    }
    ushort4v o;
    o.x = f2bf(a0); o.y = f2bf(a1); o.z = f2bf(a2); o.w = f2bf(a3);
    *(ushort4v*)(samp + (size_t)row * 256 + 4 * L) = o;
}

// ---------------------------------------------------------------------------
extern "C" void kernel_launch(void* const* d_in, const int* in_sizes, int n_in,
                              void* d_out, int out_size, void* d_ws, size_t ws_size,
                              hipStream_t stream)
{
    const float* query   = (const float*)d_in[0];
    const float* refpts  = (const float*)d_in[1];
    const float* inflat  = (const float*)d_in[2];
    const int*   spatial = (const int*)d_in[3];
    const int*   lsi     = (const int*)d_in[4];
    const float* Wv      = (const float*)d_in[5];
    const float* bv      = (const float*)d_in[6];
    const float* Woff    = (const float*)d_in[7];
    const float* boff    = (const float*)d_in[8];
    const float* Wattn   = (const float*)d_in[9];
    const float* battn   = (const float*)d_in[10];
    const float* Wout    = (const float*)d_in[11];
    const float* bout    = (const float*)d_in[12];

    unsigned short* ws = (unsigned short*)d_ws;
    const size_t MR = (size_t)MTOT * 256;
    unsigned short* q16    = ws;                       // MTOT*256
    unsigned short* in16   = q16 + MR;                 // MTOT*256
    unsigned short* v16    = in16 + MR;                // MTOT*256
    unsigned short* off16  = v16 + MR;                 // MTOT*256
    unsigned short* at16   = off16 + MR;               // MTOT*128
    unsigned short* samp16 = at16 + (size_t)MTOT * 128;// MTOT*256
    unsigned short* wvT    = samp16 + MR;              // 256*256
    unsigned short* woaT   = wvT + 65536;              // 384*256 (Woff^T | Wattn^T)
    unsigned short* woutT  = woaT + 98304;             // 256*256

    const int nElem = MTOT * 256;                      // divisible by 1024
    dim3 blk256(256);

    hipLaunchKernelGGL(cvt_bf16, dim3(nElem / 1024), blk256, 0, stream, query,  q16,  nElem);
    hipLaunchKernelGGL(cvt_bf16, dim3(nElem / 1024), blk256, 0, stream, inflat, in16, nElem);
    hipLaunchKernelGGL(transpose_cvt, dim3(256), blk256, 0, stream, Wv,    wvT,          256, 256);
    hipLaunchKernelGGL(transpose_cvt, dim3(256), blk256, 0, stream, Woff,  woaT,         256, 256);
    hipLaunchKernelGGL(transpose_cvt, dim3(128), blk256, 0, stream, Wattn, woaT + 65536, 256, 128);
    hipLaunchKernelGGL(transpose_cvt, dim3(256), blk256, 0, stream, Wout,  woutT,        256, 256);

    const int mBlocks = (MTOT + 127) / 128;            // 208
    // value GEMM: N=256, single output
    hipLaunchKernelGGL((gemm3<true>), dim3(2, mBlocks), blk256, 0, stream,
                       in16, wvT, bv, bv, 256, (void*)v16, (void*)v16, MTOT, 256, 256);
    // fused off|attn GEMM: N=384, split outputs at n1=256
    hipLaunchKernelGGL((gemm3<true>), dim3(3, mBlocks), blk256, 0, stream,
                       q16, woaT, boff, battn, 256, (void*)off16, (void*)at16, MTOT, 384, 256);

    hipLaunchKernelGGL(sample2, dim3(MTOT / 4), blk256, 0, stream,
                       v16, off16, at16, refpts, spatial, lsi, samp16);

    // output GEMM: N=256, f32 out
    hipLaunchKernelGGL((gemm3<false>), dim3(2, mBlocks), blk256, 0, stream,
                       samp16, woutT, bout, bout, 256, d_out, d_out, MTOT, 256, 256);
}

// Round 5
// 231.262 us; speedup vs baseline: 1.1951x; 1.1106x over previous
//
#include <hip/hip_runtime.h>
#include <math.h>

#define LEN_Q 13294
#define NFRAMES 2
#define MTOT (LEN_Q * NFRAMES)   // 26588
#define DMODEL 256
#define HEADS 8
#define LEVELS 4
#define POINTS 4

typedef __attribute__((ext_vector_type(8))) short short8;
typedef __attribute__((ext_vector_type(4))) float f32x4;
typedef __attribute__((ext_vector_type(2))) unsigned int uint2v;
typedef __attribute__((ext_vector_type(4))) unsigned short ushort4v;

__device__ __forceinline__ unsigned short f2bf(float x) {
    unsigned u = __builtin_bit_cast(unsigned, x);
    unsigned r = (u + 0x7fffu + ((u >> 16) & 1u)) >> 16;
    return (unsigned short)r;
}
__device__ __forceinline__ float bf2f(unsigned short b) {
    return __builtin_bit_cast(float, (unsigned)b << 16);
}

#define LSTR 40   // LDS row stride (shorts): 128*40*2 = 10 KB/matrix; 2-way-free bank pattern

// ---------------------------------------------------------------------------
// prep: all 4 weight transposes f32[K,N] -> bf16[N,K] in one dispatch.
// grid 896: [0,256) Wv, [256,512) Woff, [512,640) Wattn, [640,896) Wout.
// ---------------------------------------------------------------------------
__global__ __launch_bounds__(256) void prep_weights(
    const float* __restrict__ Wv,  const float* __restrict__ Woff,
    const float* __restrict__ Wat, const float* __restrict__ Wout,
    unsigned short* __restrict__ wvT,   // 256x256
    unsigned short* __restrict__ woaT,  // 384x256 (Woff^T rows 0-255 | Wattn^T rows 256-383)
    unsigned short* __restrict__ woutT) // 256x256
{
    const int b = blockIdx.x;
    const int k = threadIdx.x;          // 0..255
    const float* src; unsigned short* dst; int N; int n;
    if (b < 256)      { src = Wv;   dst = wvT;          N = 256; n = b; }
    else if (b < 512) { src = Woff; dst = woaT;         N = 256; n = b - 256; }
    else if (b < 640) { src = Wat;  dst = woaT + 65536; N = 128; n = b - 512; }
    else              { src = Wout; dst = woutT;        N = 256; n = b - 640; }
    dst[(size_t)n * 256 + k] = f2bf(src[(size_t)k * N + n]);
}

// ---------------------------------------------------------------------------
// Fused GEMM: one dispatch computes value = inflat@Wv+bv  (n-tiles 0,1) and
// off|attn = query@[Woff|Wattn]+[boff|battn] (n-tiles 2,3,4), with inline
// f32->bf16 conversion of A during LDS staging.
// 256 thr = 4 waves; block tile 128x128, BK=32; wave = 64x64 quadrant via
// 4x4 16x16x32 bf16 MFMAs. LDS padded to LSTR=40 shorts/row.
// ---------------------------------------------------------------------------
__global__ __launch_bounds__(256, 3) void gemm_fused(
    const float* __restrict__ Aval,      // [M,256] inflat
    const float* __restrict__ Aq,        // [M,256] query
    const unsigned short* __restrict__ BTv,   // [256,256]
    const unsigned short* __restrict__ BToa,  // [384,256]
    const float* __restrict__ bv,
    const float* __restrict__ boff,
    const float* __restrict__ battn,
    unsigned short* __restrict__ v16,    // [M,256]
    unsigned short* __restrict__ off16,  // [M,256]
    unsigned short* __restrict__ at16,   // [M,128]
    int M, int K)
{
    __shared__ unsigned short As[128 * LSTR];
    __shared__ unsigned short Bs[128 * LSTR];

    const int t = threadIdx.x;
    const int w = t >> 6;
    const int L = t & 63;
    const int m0 = blockIdx.y * 128;
    const bool isVal = (blockIdx.x < 2);
    const int nTile = isVal ? blockIdx.x : blockIdx.x - 2;
    const float* Af = isVal ? Aval : Aq;
    const unsigned short* BTb = (isVal ? BTv : BToa) + (size_t)nTile * 128 * K;

    // staging map: thread t -> row sr = t>>1, 16-col chunk sc = (t&1)*16
    const int sr = t >> 1;
    const int sc = (t & 1) * 16;
    int arow = m0 + sr; if (arow > M - 1) arow = M - 1;
    const float* Ag = Af + (size_t)arow * K + sc;
    const unsigned short* Bg = BTb + (size_t)sr * K + sc;
    unsigned short* AsW = &As[sr * LSTR + sc];
    unsigned short* BsW = &Bs[sr * LSTR + sc];

    const int mq = (w & 1) * 64;
    const int nq = (w >> 1) * 64;
    const int lr = L & 15;
    const int kq = (L >> 4) * 8;

    f32x4 acc[4][4];
    #pragma unroll
    for (int i = 0; i < 4; ++i)
        #pragma unroll
        for (int j = 0; j < 4; ++j) acc[i][j] = (f32x4){0.f, 0.f, 0.f, 0.f};

    for (int k0 = 0; k0 < K; k0 += 32) {
        f32x4 a0 = *(const f32x4*)(Ag + k0);
        f32x4 a1 = *(const f32x4*)(Ag + k0 + 4);
        f32x4 a2 = *(const f32x4*)(Ag + k0 + 8);
        f32x4 a3 = *(const f32x4*)(Ag + k0 + 12);
        short8 b0 = *(const short8*)(Bg + k0);
        short8 b1 = *(const short8*)(Bg + k0 + 8);
        short8 p0, p1;
        p0[0]=(short)f2bf(a0.x); p0[1]=(short)f2bf(a0.y); p0[2]=(short)f2bf(a0.z); p0[3]=(short)f2bf(a0.w);
        p0[4]=(short)f2bf(a1.x); p0[5]=(short)f2bf(a1.y); p0[6]=(short)f2bf(a1.z); p0[7]=(short)f2bf(a1.w);
        p1[0]=(short)f2bf(a2.x); p1[1]=(short)f2bf(a2.y); p1[2]=(short)f2bf(a2.z); p1[3]=(short)f2bf(a2.w);
        p1[4]=(short)f2bf(a3.x); p1[5]=(short)f2bf(a3.y); p1[6]=(short)f2bf(a3.z); p1[7]=(short)f2bf(a3.w);
        __syncthreads();
        *(short8*)(AsW) = p0;
        *(short8*)(AsW + 8) = p1;
        *(short8*)(BsW) = b0;
        *(short8*)(BsW + 8) = b1;
        __syncthreads();

        short8 af[4], bf[4];
        #pragma unroll
        for (int i = 0; i < 4; ++i)
            af[i] = *(const short8*)&As[(mq + i * 16 + lr) * LSTR + kq];
        #pragma unroll
        for (int j = 0; j < 4; ++j)
            bf[j] = *(const short8*)&Bs[(nq + j * 16 + lr) * LSTR + kq];
        #pragma unroll
        for (int i = 0; i < 4; ++i)
            #pragma unroll
            for (int j = 0; j < 4; ++j)
                acc[i][j] = __builtin_amdgcn_mfma_f32_16x16x32_bf16(af[i], bf[j], acc[i][j], 0, 0, 0);
    }

    const int rr = (L >> 4) * 4;
    #pragma unroll
    for (int i = 0; i < 4; ++i) {
        #pragma unroll
        for (int r = 0; r < 4; ++r) {
            int m = m0 + mq + i * 16 + rr + r;
            if (m < M) {
                #pragma unroll
                for (int j = 0; j < 4; ++j) {
                    int colg = nTile * 128 + nq + j * 16 + lr;
                    float v = acc[i][j][r];
                    if (isVal) {
                        v16[(size_t)m * 256 + colg] = f2bf(v + bv[colg]);
                    } else if (colg < 256) {
                        off16[(size_t)m * 256 + colg] = f2bf(v + boff[colg]);
                    } else {
                        at16[(size_t)m * 128 + (colg - 256)] = f2bf(v + battn[colg - 256]);
                    }
                }
            }
        }
    }
}

// ---------------------------------------------------------------------------
// Output GEMM: C[M,256] f32 = A[M,256](bf16) @ woutT^T + bout. Same structure.
// ---------------------------------------------------------------------------
__global__ __launch_bounds__(256, 3) void gemm_out(
    const unsigned short* __restrict__ A,
    const unsigned short* __restrict__ BT,
    const float* __restrict__ bias,
    float* __restrict__ C,
    int M, int K)
{
    __shared__ unsigned short As[128 * LSTR];
    __shared__ unsigned short Bs[128 * LSTR];

    const int t = threadIdx.x;
    const int w = t >> 6;
    const int L = t & 63;
    const int m0 = blockIdx.y * 128;
    const int n0 = blockIdx.x * 128;

    const int sr = t >> 1;
    const int sc = (t & 1) * 16;
    int arow = m0 + sr; if (arow > M - 1) arow = M - 1;
    const unsigned short* Ag = A + (size_t)arow * K + sc;
    const unsigned short* Bg = BT + (size_t)(n0 + sr) * K + sc;
    unsigned short* AsW = &As[sr * LSTR + sc];
    unsigned short* BsW = &Bs[sr * LSTR + sc];

    const int mq = (w & 1) * 64;
    const int nq = (w >> 1) * 64;
    const int lr = L & 15;
    const int kq = (L >> 4) * 8;

    f32x4 acc[4][4];
    #pragma unroll
    for (int i = 0; i < 4; ++i)
        #pragma unroll
        for (int j = 0; j < 4; ++j) acc[i][j] = (f32x4){0.f, 0.f, 0.f, 0.f};

    for (int k0 = 0; k0 < K; k0 += 32) {
        short8 a0 = *(const short8*)(Ag + k0);
        short8 a1 = *(const short8*)(Ag + k0 + 8);
        short8 b0 = *(const short8*)(Bg + k0);
        short8 b1 = *(const short8*)(Bg + k0 + 8);
        __syncthreads();
        *(short8*)(AsW) = a0;
        *(short8*)(AsW + 8) = a1;
        *(short8*)(BsW) = b0;
        *(short8*)(BsW + 8) = b1;
        __syncthreads();

        short8 af[4], bf[4];
        #pragma unroll
        for (int i = 0; i < 4; ++i)
            af[i] = *(const short8*)&As[(mq + i * 16 + lr) * LSTR + kq];
        #pragma unroll
        for (int j = 0; j < 4; ++j)
            bf[j] = *(const short8*)&Bs[(nq + j * 16 + lr) * LSTR + kq];
        #pragma unroll
        for (int i = 0; i < 4; ++i)
            #pragma unroll
            for (int j = 0; j < 4; ++j)
                acc[i][j] = __builtin_amdgcn_mfma_f32_16x16x32_bf16(af[i], bf[j], acc[i][j], 0, 0, 0);
    }

    const int rr = (L >> 4) * 4;
    #pragma unroll
    for (int i = 0; i < 4; ++i) {
        #pragma unroll
        for (int r = 0; r < 4; ++r) {
            int m = m0 + mq + i * 16 + rr + r;
            if (m < M) {
                #pragma unroll
                for (int j = 0; j < 4; ++j) {
                    int n = n0 + nq + j * 16 + lr;
                    C[(size_t)m * 256 + n] = acc[i][j][r] + bias[n];
                }
            }
        }
    }
}

// ---------------------------------------------------------------------------
// Sampler: R2 structure + XCD-aware block swizzle (contiguous query chunk per
// XCD -> one frame's 6.8 MB value working set per XCD L2) + byte-prescaled
// indices + rcp instead of divide. Grid 6648 = 8*831; newb bijective.
// ---------------------------------------------------------------------------
__global__ __launch_bounds__(256) void sample2x(
    const unsigned short* __restrict__ value,  // bf16 [MTOT,256]
    const unsigned short* __restrict__ off,    // bf16 [MTOT,256]
    const unsigned short* __restrict__ attn,   // bf16 [MTOT,128]
    const float* __restrict__ refpts,          // [LEN_Q, LEVELS, 2]
    const int*   __restrict__ spatial,         // [LEVELS,2] (H,W)
    const int*   __restrict__ lsi,             // [LEVELS]
    unsigned short* __restrict__ samp)         // bf16 [MTOT,256]
{
    const int b = blockIdx.x;
    const int newb = (b & 7) * 831 + (b >> 3);   // XCD x gets chunk x
    if (newb * 4 >= MTOT) return;                // only block newb==6647 exits (whole block)
    const int w = threadIdx.x >> 6;
    const int L = threadIdx.x & 63;
    const int row = newb * 4 + w;
    const int frame = row >= LEN_Q ? 1 : 0;
    const int q = row - frame * LEN_Q;

    __shared__ float attn_s[4][HEADS][16];
    __shared__ float loc_s[4][HEADS][16][2];
    __shared__ float w_s[4][HEADS][16][4];
    __shared__ int   idx_s[4][HEADS][16][4];

    // ---- phase 1: off -> loc, attn -> LDS ----
    {
        uint2v ov = *(const uint2v*)(off + (size_t)row * 256 + 4 * L);
        float o[4];
        o[0] = bf2f((unsigned short)(ov.x & 0xffffu));
        o[1] = bf2f((unsigned short)(ov.x >> 16));
        o[2] = bf2f((unsigned short)(ov.y & 0xffffu));
        o[3] = bf2f((unsigned short)(ov.y >> 16));
        #pragma unroll
        for (int i = 0; i < 4; ++i) {
            int tt = 4 * L + i;
            int c = tt & 1;
            int l = (tt >> 3) & 3;
            int h = tt >> 5;
            int lp = (tt >> 1) & 15;
            float r = refpts[((size_t)q * LEVELS + l) * 2 + c];
            int dim = spatial[l * 2 + (c ^ 1)];   // c==0 -> W, c==1 -> H
            loc_s[w][h][lp][c] = r + o[i] * __builtin_amdgcn_rcpf((float)dim);
        }
        unsigned av = *(const unsigned*)(attn + (size_t)row * 128 + 2 * L);
        int t0 = 2 * L;
        attn_s[w][t0 >> 4][t0 & 15] = bf2f((unsigned short)(av & 0xffffu));
        attn_s[w][(t0 + 1) >> 4][(t0 + 1) & 15] = bf2f((unsigned short)(av >> 16));
    }
    __syncthreads();

    // ---- phase 2: softmax per head ----
    if (L < 8) {
        float m = attn_s[w][L][0];
        #pragma unroll
        for (int i = 1; i < 16; ++i) m = fmaxf(m, attn_s[w][L][i]);
        float e[16]; float s = 0.f;
        #pragma unroll
        for (int i = 0; i < 16; ++i) { e[i] = __expf(attn_s[w][L][i] - m); s += e[i]; }
        float inv = 1.f / s;
        #pragma unroll
        for (int i = 0; i < 16; ++i) attn_s[w][L][i] = e[i] * inv;
    }
    __syncthreads();

    // ---- phase 3: corner idx (byte-prescaled) + weight ----
    #pragma unroll
    for (int i = 0; i < 2; ++i) {
        int e = 2 * L + i;
        int h = e >> 4;
        int lp = e & 15;
        int l = lp >> 2;
        int Hl = spatial[l * 2], Wl = spatial[l * 2 + 1];
        int start = lsi[l];
        float wt = attn_s[w][h][lp];
        float x = loc_s[w][h][lp][0] * (float)Wl - 0.5f;
        float y = loc_s[w][h][lp][1] * (float)Hl - 0.5f;
        float x0f = floorf(x), y0f = floorf(y);
        float lx = x - x0f, ly = y - y0f;
        int x0 = (int)x0f, y0 = (int)y0f;
        int x1 = x0 + 1, y1 = y0 + 1;
        int vx0 = (x0 >= 0) & (x0 < Wl);
        int vx1 = (x1 >= 0) & (x1 < Wl);
        int vy0 = (y0 >= 0) & (y0 < Hl);
        int vy1 = (y1 >= 0) & (y1 < Hl);
        int x0c = min(max(x0, 0), Wl - 1);
        int x1c = min(max(x1, 0), Wl - 1);
        int y0c = min(max(y0, 0), Hl - 1);
        int y1c = min(max(y1, 0), Hl - 1);
        idx_s[w][h][lp][0] = (start + y0c * Wl + x0c) * 512;   // byte offset
        idx_s[w][h][lp][1] = (start + y0c * Wl + x1c) * 512;
        idx_s[w][h][lp][2] = (start + y1c * Wl + x0c) * 512;
        idx_s[w][h][lp][3] = (start + y1c * Wl + x1c) * 512;
        w_s[w][h][lp][0] = (vy0 & vx0) ? wt * (1.f - lx) * (1.f - ly) : 0.f;
        w_s[w][h][lp][1] = (vy0 & vx1) ? wt * lx * (1.f - ly) : 0.f;
        w_s[w][h][lp][2] = (vy1 & vx0) ? wt * (1.f - lx) * ly : 0.f;
        w_s[w][h][lp][3] = (vy1 & vx1) ? wt * lx * ly : 0.f;
    }
    __syncthreads();

    // ---- phase 4: gather (bf16x4 per lane) ----
    const int h = L >> 3;
    const char* vbase = (const char*)value + (size_t)frame * LEN_Q * 512 + 8 * L;
    float a0 = 0.f, a1 = 0.f, a2 = 0.f, a3 = 0.f;
    #pragma unroll
    for (int lp = 0; lp < 16; ++lp) {
        #pragma unroll
        for (int cr = 0; cr < 4; ++cr) {
            float wt = w_s[w][h][lp][cr];
            int idx = idx_s[w][h][lp][cr];
            uint2v v = *(const uint2v*)(vbase + (size_t)idx);
            a0 = fmaf(wt, __builtin_bit_cast(float, v.x << 16), a0);
            a1 = fmaf(wt, __builtin_bit_cast(float, v.x & 0xffff0000u), a1);
            a2 = fmaf(wt, __builtin_bit_cast(float, v.y << 16), a2);
            a3 = fmaf(wt, __builtin_bit_cast(float, v.y & 0xffff0000u), a3);
        }
    }
    ushort4v o;
    o.x = f2bf(a0); o.y = f2bf(a1); o.z = f2bf(a2); o.w = f2bf(a3);
    *(ushort4v*)(samp + (size_t)row * 256 + 4 * L) = o;
}

// ---------------------------------------------------------------------------
extern "C" void kernel_launch(void* const* d_in, const int* in_sizes, int n_in,
                              void* d_out, int out_size, void* d_ws, size_t ws_size,
                              hipStream_t stream)
{
    const float* query   = (const float*)d_in[0];
    const float* refpts  = (const float*)d_in[1];
    const float* inflat  = (const float*)d_in[2];
    const int*   spatial = (const int*)d_in[3];
    const int*   lsi     = (const int*)d_in[4];
    const float* Wv      = (const float*)d_in[5];
    const float* bv      = (const float*)d_in[6];
    const float* Woff    = (const float*)d_in[7];
    const float* boff    = (const float*)d_in[8];
    const float* Wattn   = (const float*)d_in[9];
    const float* battn   = (const float*)d_in[10];
    const float* Wout    = (const float*)d_in[11];
    const float* bout    = (const float*)d_in[12];

    unsigned short* ws = (unsigned short*)d_ws;
    const size_t MR = (size_t)MTOT * 256;
    unsigned short* v16    = ws;                        // MTOT*256
    unsigned short* off16  = v16 + MR;                  // MTOT*256
    unsigned short* at16   = off16 + MR;                // MTOT*128
    unsigned short* samp16 = at16 + (size_t)MTOT * 128; // MTOT*256
    unsigned short* wvT    = samp16 + MR;               // 256*256
    unsigned short* woaT   = wvT + 65536;               // 384*256
    unsigned short* woutT  = woaT + 98304;              // 256*256

    dim3 blk256(256);
    const int mBlocks = (MTOT + 127) / 128;             // 208

    hipLaunchKernelGGL(prep_weights, dim3(896), blk256, 0, stream,
                       Wv, Woff, Wattn, Wout, wvT, woaT, woutT);

    hipLaunchKernelGGL(gemm_fused, dim3(5, mBlocks), blk256, 0, stream,
                       inflat, query, wvT, woaT, bv, boff, battn,
                       v16, off16, at16, MTOT, 256);

    hipLaunchKernelGGL(sample2x, dim3(6648), blk256, 0, stream,
                       v16, off16, at16, refpts, spatial, lsi, samp16);

    hipLaunchKernelGGL(gemm_out, dim3(2, mBlocks), blk256, 0, stream,
                       samp16, woutT, bout, (float*)d_out, MTOT, 256);
}